// Round 10
// baseline (111.285 us; speedup 1.0000x reference)
//
#include <hip/hip_runtime.h>

typedef int v4i  __attribute__((ext_vector_type(4)));
typedef int v16i __attribute__((ext_vector_type(16)));

// ---- problem constants ----
#define N_IMG   32
#define C_IN    256
#define HWDIM   56
#define HW2     3136            // 56*56
#define OUT_TOT 25690112        // 32*256*56*56
#define OUT_NSTR 802816         // 256*3136

// padded NHWC int8, 256 B/pixel, granule-swizzled: granule g' = g ^ (pixel&15)
#define PXB     256
#define PPI     3364            // 58*58 padded pixels per image
#define XP_IMG  861184          // PPI*PXB bytes per image
#define XP_SLACK 4096
// packed weights, phase-major: [phase:72][cb2:8][lane:64][16B] = 8 KB/phase
#define WP_BYTES  589824ull

// main kernel: 64 outputs per block -> X window 184 px; W ring 4 x 8 KB
#define S_TILE  64
#define TILES_PER_IMG 49        // 3136/64 exact -> no masking
#define WIN_B   47104           // 184*256
#define WRING_B 32768
#define LDSB    (WIN_B + WRING_B)   // 79872 -> 2 blocks/CU

// ---------- pre-pass A: x NCHW int32 -> swizzled padded NHWC int8 ----------
__global__ void dc_x_to_nhwc(const int* __restrict__ x, unsigned int* __restrict__ x8,
                             int n0) {
    __shared__ unsigned int lds[64 * 65];
    const int t = threadIdx.x;
    const int w = t & 63, qq = t >> 6;
    const int nl = blockIdx.x / HWDIM, h = blockIdx.x % HWDIM;

    if (w < HWDIM) {
        const int* xb = x + (size_t)(n0 + nl) * OUT_NSTR + h * HWDIM + w;
        #pragma unroll
        for (int it = 0; it < 16; ++it) {
            const int cg4 = qq * 16 + it;
            const int ci0 = cg4 * 4;
            unsigned v  =  ((unsigned)xb[(ci0 + 0) * HW2] & 0xff);
            v |= ((unsigned)xb[(ci0 + 1) * HW2] & 0xff) << 8;
            v |= ((unsigned)xb[(ci0 + 2) * HW2] & 0xff) << 16;
            v |= ((unsigned)xb[(ci0 + 3) * HW2] & 0xff) << 24;
            lds[w * 65 + cg4] = v;
        }
    }
    __syncthreads();
    // write pixel P = (h+1)*58 + (w2+1), dword cg permuted: granule ^= P&15
    unsigned int* ob = x8 + (size_t)nl * (XP_IMG / 4) + ((h + 1) * 58 + 1) * (PXB / 4);
    #pragma unroll
    for (int it = 0; it < 14; ++it) {
        const int f = it * 256 + t;
        const int w2 = f >> 6, cg = f & 63;
        if (w2 < HWDIM) {
            const int key = ((h + 1) * 58 + w2 + 1) & 15;
            const int cg2 = (((cg >> 2) ^ key) << 2) | (cg & 3);
            ob[w2 * (PXB / 4) + cg2] = lds[w2 * 65 + cg];
        }
    }
}

// ---------- halo-ring zero (zeros are swizzle-invariant) ----------
__global__ void dc_halo(unsigned int* __restrict__ x8) {
    const int nl = blockIdx.x;
    const int t = threadIdx.x;
    if (t < 228) {
        int h, w;
        if (t < 58)       { h = 0;        w = t; }
        else if (t < 116) { h = 57;       w = t - 58; }
        else if (t < 172) { h = t - 115;  w = 0; }
        else              { h = t - 171;  w = 57; }
        unsigned int* p = x8 + ((size_t)nl * PPI + h * 58 + w) * (PXB / 4);
        #pragma unroll
        for (int i = 0; i < PXB / 4; ++i) p[i] = 0;
    }
}

// ---------- pre-pass B: pack weights phase-major ----------
// dst granule (phase=t*8+kb, cb2, l) holds W[co=cb2*32+(l&31)][ci=kb*32+(l>>5)*16+j]
__global__ void dc_pack_w(const int* __restrict__ wt, unsigned int* __restrict__ wp) {
    const int tid = blockIdx.x * 256 + threadIdx.x;  // < 147456
    const int jq = tid & 3;
    const int l  = (tid >> 2) & 63;
    const int kb = (tid >> 8) & 7;
    const int r  = tid >> 11;          // 0..71
    const int t  = r % 9;
    const int cb2 = r / 9;             // 0..7
    const int co  = cb2 * 32 + (l & 31);
    const int ci0 = kb * 32 + (l >> 5) * 16 + jq * 4;
    const int kh = t / 3, kw = t - kh * 3;
    unsigned v = 0;
    #pragma unroll
    for (int k = 0; k < 4; ++k) {
        unsigned b = (unsigned)wt[((co * C_IN + ci0 + k) * 3 + kh) * 3 + kw];
        v |= (b & 0xff) << (8 * k);
    }
    const int dst = (((t * 8 + kb) * 8 + cb2) * 64 + l) * 4 + jq;
    wp[dst] = v;
}

__device__ __forceinline__ void gll16(const char* g, char* l) {
    __builtin_amdgcn_global_load_lds(
        (const __attribute__((address_space(1))) unsigned int*)g,
        (__attribute__((address_space(3))) unsigned int*)l, 16, 0, 0);
}

// ---------- main kernel: counted-vmcnt W pipeline, X LDS-resident -----------
// 256 thr (4 waves co4xs1), wave = 64co x 64s (acc[2][2]); 2 blocks/CU.
// Phase j=(tap,kb): stage W(j+2) -> vmcnt(4) -> s_barrier -> ds_read -> 4 MFMA.
__global__ __launch_bounds__(256, 2) void dc_mfma(const char* __restrict__ x8,
                                                  const char* __restrict__ wp,
                                                  int* __restrict__ out, int nwg) {
    extern __shared__ __align__(16) char xs[];
    char* wring = xs + WIN_B;

    // bijective XCD swizzle (m204)
    const int bid = blockIdx.x;
    const int q = nwg >> 3, r = nwg & 7;
    const int xcd = bid & 7, bidx = bid >> 3;
    const int wgid = (xcd < r ? xcd * (q + 1) : r * (q + 1) + (xcd - r) * q) + bidx;

    const int nl = wgid / TILES_PER_IMG, st = wgid - nl * TILES_PER_IMG;

    const int tid = threadIdx.x;
    const int l = tid & 63, wid = tid >> 6;
    const int lane31 = l & 31, hi = l >> 5;

    // ---- stage X window: padded pixels [p0, p0+184) ----
    const int hw0 = st * S_TILE;
    const int h0 = hw0 / HWDIM, w0 = hw0 - h0 * HWDIM;
    const int p0 = h0 * 58 + w0;                 // = first-output-pixel - 59
    const char* gsrc = x8 + (size_t)nl * XP_IMG + (size_t)p0 * PXB;

    #pragma unroll
    for (int c = 0; c < 12; ++c) {               // 184*256 = 47104 B
        const int off = (c * 256 + tid) * 16;
        if (off < WIN_B) gll16(gsrc + off, xs + off);
    }

    // ---- stage W phases 0,1 (ring slots 0,1) ----
    const char* wsrc = wp + tid * 16;
    char* wdst = wring + tid * 16;
    gll16(wsrc,            wdst);
    gll16(wsrc + 4096,     wdst + 4096);
    gll16(wsrc + 8192,     wdst + 8192);
    gll16(wsrc + 12288,    wdst + 12288);

    // ---- per-lane setup while DMA flies ----
    int rbase[2], Pb[2], outb[2];
    #pragma unroll
    for (int ni = 0; ni < 2; ++ni) {
        const int hw = hw0 + ni * 32 + lane31;
        const int h = hw / HWDIM, w = hw - h * HWDIM;
        Pb[ni] = (h + 1) * 58 + (w + 1);         // local padded pixel
        rbase[ni] = Pb[ni] - p0;                 // in [59, 124]
        outb[ni] = nl * OUT_NSTR + hw;
    }

    asm volatile("s_waitcnt vmcnt(2)" ::: "memory");   // X + W(0) landed
    __builtin_amdgcn_sched_barrier(0);
    __builtin_amdgcn_s_barrier();
    __builtin_amdgcn_sched_barrier(0);

    const int dtap[9] = {-59, -58, -57, -1, 0, 1, 57, 58, 59};
    v16i acc[2][2] = {};

    #pragma unroll
    for (int t = 0; t < 9; ++t) {
        // per-tap swizzled X base: granule g' = (hi + 2kb) ^ (P & 15)
        int xbase[2], xkey[2];
        #pragma unroll
        for (int ni = 0; ni < 2; ++ni) {
            const int rt = rbase[ni] + dtap[t];
            const int key = (Pb[ni] + dtap[t]) & 15;
            xbase[ni] = rt * PXB + ((hi ^ (key & 1)) << 4);
            xkey[ni] = (key >> 1) & 7;
        }
        #pragma unroll
        for (int kb = 0; kb < 8; ++kb) {
            const int j = t * 8 + kb;
            if (j + 2 < 72) {                    // stage W(j+2), ring slot (j+2)&3
                const int pn = j + 2, slot = pn & 3;
                gll16(wsrc + pn * 8192,        wdst + slot * 8192);
                gll16(wsrc + pn * 8192 + 4096, wdst + slot * 8192 + 4096);
            }
            if (j < 70)       asm volatile("s_waitcnt vmcnt(4)" ::: "memory");
            else if (j == 70) asm volatile("s_waitcnt vmcnt(2)" ::: "memory");
            else              asm volatile("s_waitcnt vmcnt(0)" ::: "memory");
            __builtin_amdgcn_sched_barrier(0);
            __builtin_amdgcn_s_barrier();
            __builtin_amdgcn_sched_barrier(0);

            const char* wslot = wring + (j & 3) * 8192 + l * 16;
            const v4i wf0 = *(const v4i*)(wslot + (wid * 2 + 0) * 1024);
            const v4i wf1 = *(const v4i*)(wslot + (wid * 2 + 1) * 1024);
            const v4i xf0 = *(const v4i*)(xs + xbase[0] + ((kb ^ xkey[0]) << 5));
            const v4i xf1 = *(const v4i*)(xs + xbase[1] + ((kb ^ xkey[1]) << 5));

            __builtin_amdgcn_s_setprio(1);
            acc[0][0] = __builtin_amdgcn_mfma_i32_32x32x32_i8(wf0, xf0, acc[0][0], 0, 0, 0);
            acc[0][1] = __builtin_amdgcn_mfma_i32_32x32x32_i8(wf0, xf1, acc[0][1], 0, 0, 0);
            acc[1][0] = __builtin_amdgcn_mfma_i32_32x32x32_i8(wf1, xf0, acc[1][0], 0, 0, 0);
            acc[1][1] = __builtin_amdgcn_mfma_i32_32x32x32_i8(wf1, xf1, acc[1][1], 0, 0, 0);
            __builtin_amdgcn_s_setprio(0);
        }
    }

    // C/D: col = lane&31 (spatial), row = (r&3)+8*(r>>2)+4*hi (co)
    #pragma unroll
    for (int mi = 0; mi < 2; ++mi) {
        #pragma unroll
        for (int ni = 0; ni < 2; ++ni) {
            const v16i c = acc[mi][ni];
            int* ob = out + outb[ni] + (wid * 64 + mi * 32 + 4 * hi) * HW2;
            #pragma unroll
            for (int rr = 0; rr < 16; ++rr) {
                __builtin_nontemporal_store(c[rr], ob + ((rr & 3) + 8 * (rr >> 2)) * HW2);
            }
        }
    }
}

// ---------- fallback: direct conv (correct, slow) ----------
__global__ void dc_naive(const int* __restrict__ x, const int* __restrict__ wt,
                         int* __restrict__ out) {
    const int idx = blockIdx.x * 256 + threadIdx.x;
    if (idx >= OUT_TOT) return;
    const int w = idx % HWDIM;
    const int h = (idx / HWDIM) % HWDIM;
    const int co = (idx / HW2) & 255;
    const int n = idx / OUT_NSTR;
    const int* xn = x + n * OUT_NSTR;
    const int* wo = wt + co * (C_IN * 9);
    int acc = 0;
    for (int ci = 0; ci < C_IN; ++ci) {
        const int* xc = xn + ci * HW2;
        const int* wc = wo + ci * 9;
        #pragma unroll
        for (int kh = 0; kh < 3; ++kh) {
            const int hh = h + kh - 1;
            if ((unsigned)hh >= HWDIM) continue;
            #pragma unroll
            for (int kw = 0; kw < 3; ++kw) {
                const int ww = w + kw - 1;
                if ((unsigned)ww >= HWDIM) continue;
                acc += xc[hh * HWDIM + ww] * wc[kh * 3 + kw];
            }
        }
    }
    out[idx] = acc;
}

extern "C" void kernel_launch(void* const* d_in, const int* in_sizes, int n_in,
                              void* d_out, int out_size, void* d_ws, size_t ws_size,
                              hipStream_t stream) {
    const int* x  = (const int*)d_in[0];
    const int* wt = (const int*)d_in[1];
    int* out = (int*)d_out;

    int chunk = 0;
    const int cand[4] = {32, 16, 8, 4};
    for (int i = 0; i < 4; ++i) {
        if ((size_t)cand[i] * XP_IMG + XP_SLACK + WP_BYTES <= ws_size) { chunk = cand[i]; break; }
    }

    if (chunk > 0) {
        char* x8 = (char*)d_ws;
        const size_t x8_bytes = (size_t)chunk * XP_IMG + XP_SLACK;
        unsigned int* wp = (unsigned int*)(x8 + x8_bytes);
        hipLaunchKernelGGL(dc_halo, dim3(chunk), dim3(256), 0, stream, (unsigned int*)x8);
        hipLaunchKernelGGL(dc_pack_w, dim3(576), dim3(256), 0, stream, wt, wp);
        for (int n0 = 0; n0 < N_IMG; n0 += chunk) {
            hipLaunchKernelGGL(dc_x_to_nhwc, dim3(chunk * HWDIM), dim3(256), 0, stream,
                               x, (unsigned int*)x8, n0);
            const int nwg = chunk * TILES_PER_IMG;
            hipLaunchKernelGGL(dc_mfma, dim3(nwg), dim3(256), LDSB, stream,
                               (const char*)x8, (const char*)wp,
                               out + (size_t)n0 * OUT_NSTR, nwg);
        }
        return;
    }

    hipLaunchKernelGGL(dc_naive, dim3((OUT_TOT + 255) / 256), dim3(256), 0, stream,
                       x, wt, out);
}

// Round 11
// 93.461 us; speedup vs baseline: 1.1907x; 1.1907x over previous
//
#include <hip/hip_runtime.h>

typedef int v4i  __attribute__((ext_vector_type(4)));
typedef int v16i __attribute__((ext_vector_type(16)));

// ---- problem constants ----
#define N_IMG   32
#define C_IN    256
#define HWDIM   56
#define HW2     3136            // 56*56
#define OUT_TOT 25690112        // 32*256*56*56
#define OUT_NSTR 802816         // 256*3136

// padded NHWC int8, PXB bytes per pixel (256 data + 16 pad; 16B-aligned for gll16)
#define PXB     272
#define PPI     3364            // 58*58 padded pixels per image
#define XP_IMG  915008          // PPI*PXB bytes per image
#define XP_SLACK 4096
// packed weights: [cb2:8][tap:9][kb:8][lane:64][16B]
#define WP_CB2STR 73728
#define WP_BYTES  589824ull

// main-kernel tiling: 64 spatial px per block -> X window 184 px
#define S_TILE  64
#define TILES_PER_IMG 49        // 3136/64 exact -> no masking
#define WIN_B   50048           // 184*272; 3 blocks/CU

// ---------- pre-pass A: x NCHW int32 -> padded NHWC int8 (272B/pixel) ----------
__global__ void dc_x_to_nhwc(const int* __restrict__ x, unsigned int* __restrict__ x8,
                             int n0) {
    __shared__ unsigned int lds[64 * 65];
    const int t = threadIdx.x;
    const int w = t & 63, q = t >> 6;
    const int nl = blockIdx.x / HWDIM, h = blockIdx.x % HWDIM;

    if (w < HWDIM) {
        const int* xb = x + (size_t)(n0 + nl) * OUT_NSTR + h * HWDIM + w;
        #pragma unroll
        for (int it = 0; it < 16; ++it) {
            const int cg4 = q * 16 + it;
            const int ci0 = cg4 * 4;
            unsigned v  =  ((unsigned)xb[(ci0 + 0) * HW2] & 0xff);
            v |= ((unsigned)xb[(ci0 + 1) * HW2] & 0xff) << 8;
            v |= ((unsigned)xb[(ci0 + 2) * HW2] & 0xff) << 16;
            v |= ((unsigned)xb[(ci0 + 3) * HW2] & 0xff) << 24;
            lds[w * 65 + cg4] = v;
        }
    }
    __syncthreads();
    unsigned int* ob = x8 + (size_t)nl * (PPI * (PXB / 4)) + ((h + 1) * 58 + 1) * (PXB / 4);
    #pragma unroll
    for (int it = 0; it < 14; ++it) {
        const int f = it * 256 + t;
        const int w2 = f >> 6, cg = f & 63;
        if (w2 < HWDIM) ob[w2 * (PXB / 4) + cg] = lds[w2 * 65 + cg];
    }
}

// ---------- halo-ring zero ----------
__global__ void dc_halo(unsigned int* __restrict__ x8) {
    const int nl = blockIdx.x;
    const int t = threadIdx.x;
    if (t < 228) {
        int h, w;
        if (t < 58)       { h = 0;        w = t; }
        else if (t < 116) { h = 57;       w = t - 58; }
        else if (t < 172) { h = t - 115;  w = 0; }
        else              { h = t - 171;  w = 57; }
        unsigned int* p = x8 + ((size_t)nl * PPI + h * 58 + w) * (PXB / 4);
        #pragma unroll
        for (int i = 0; i < PXB / 4; ++i) p[i] = 0;
    }
}

// ---------- pre-pass B: pack weights into per-lane fragment order ----------
__global__ void dc_pack_w(const int* __restrict__ wt, unsigned int* __restrict__ wp) {
    const int tid = blockIdx.x * 256 + threadIdx.x;  // < 147456
    const int jq = tid & 3;
    const int l  = (tid >> 2) & 63;
    const int kb = (tid >> 8) & 7;
    const int r  = tid >> 11;          // 0..71
    const int t  = r % 9;
    const int cb2 = r / 9;             // 0..7
    const int co  = cb2 * 32 + (l & 31);
    const int ci0 = kb * 32 + (l >> 5) * 16 + jq * 4;
    const int kh = t / 3, kw = t - kh * 3;
    unsigned v = 0;
    #pragma unroll
    for (int k = 0; k < 4; ++k) {
        unsigned b = (unsigned)wt[((co * C_IN + ci0 + k) * 3 + kh) * 3 + kw];
        v |= (b & 0xff) << (8 * k);
    }
    wp[tid] = v;
}

__device__ __forceinline__ void gll16(const char* g, char* l) {
    __builtin_amdgcn_global_load_lds(
        (const __attribute__((address_space(1))) unsigned int*)g,
        (__attribute__((address_space(3))) unsigned int*)l, 16, 0, 0);
}

// pinned 16B global load: issue point fixed by volatile asm (compiler can't sink)
__device__ __forceinline__ v4i gload16(const char* p) {
    v4i r;
    asm volatile("global_load_dwordx4 %0, %1, off"
                 : "=v"(r) : "v"(p) : "memory");
    return r;
}

// ---------- main kernel: 256co x 64s per block, 4 waves, 3 blocks/CU ----------
// wave = 64co x 64s (acc[2][2]); X window in LDS; barrier-free K-loop.
// R11: W ring via volatile-asm loads, depth 5, counted vmcnt (AITER pattern).
__global__ __launch_bounds__(256, 3) void dc_mfma(const char* __restrict__ x8,
                                                  const char* __restrict__ wp,
                                                  int* __restrict__ out, int nwg) {
    extern __shared__ __align__(16) char xs[];

    // bijective XCD swizzle (m204)
    const int bid = blockIdx.x;
    const int q = nwg >> 3, r = nwg & 7;
    const int xcd = bid & 7, bidx = bid >> 3;
    const int wgid = (xcd < r ? xcd * (q + 1) : r * (q + 1) + (xcd - r) * q) + bidx;

    const int nl = wgid / TILES_PER_IMG, st = wgid - nl * TILES_PER_IMG;

    const int tid = threadIdx.x;
    const int l = tid & 63, wid = tid >> 6;
    const int lane31 = l & 31, hi = l >> 5;

    // stage window: padded pixels [p0, p0+184) of this image; p0 = h0*58 + w0
    const int hw0 = st * S_TILE;
    const int h0 = hw0 / HWDIM, w0 = hw0 - h0 * HWDIM;
    const int p0 = h0 * 58 + w0;
    const char* gsrc = x8 + (size_t)nl * XP_IMG + (size_t)p0 * PXB;

    #pragma unroll
    for (int c = 0; c < 13; ++c) {             // 13*256*16 = 53248 >= 50048
        const int off = (c * 256 + tid) * 16;
        if (off < WIN_B) gll16(gsrc + off, xs + off);
    }

    // per-s-fragment setup (2 frags of 32 spatial) while DMA flies
    int breg[2], outb[2];
    #pragma unroll
    for (int ni = 0; ni < 2; ++ni) {
        const int hw = hw0 + ni * 32 + lane31;
        const int h = hw / HWDIM, w = hw - h * HWDIM;
        const int p = (h + 1) * 58 + (w + 1);
        breg[ni] = (p - p0) * PXB + hi * 16 - 16048;   // >= 0 after +xoffp
        outb[ni] = nl * OUT_NSTR + hw;
    }

    // wave wid owns co = wid*64 .. +63  (cb2 = wid*2, wid*2+1)
    const char* wb0 = wp + (wid * 2) * WP_CB2STR + l * 16;
    const char* wb1 = wb0 + WP_CB2STR;

    const int xoffp[9] = {
        16048 - 59 * PXB, 16048 - 58 * PXB, 16048 - 57 * PXB,
        16048 - 1 * PXB,  16048,            16048 + 1 * PXB,
        16048 + 57 * PXB, 16048 + 58 * PXB, 16048 + 59 * PXB
    };

    __syncthreads();                           // X staged (vmcnt(0) inside); no more barriers

    v16i acc[2][2] = {};
    v4i wa[8][2];                              // 8-slot ring, prefetch distance 5 (pinned)
    v4i xb[2][2];                              // depth-1 X prefetch ring (LDS)

    #pragma unroll
    for (int d = 0; d < 5; ++d) {              // ring prologue: stays in flight
        wa[d][0] = gload16(wb0 + d * 1024);
        wa[d][1] = gload16(wb1 + d * 1024);
    }

    xb[0][0] = *(const v4i*)(xs + breg[0] + xoffp[0]);
    xb[0][1] = *(const v4i*)(xs + breg[1] + xoffp[0]);

    #pragma unroll
    for (int j = 0; j < 72; ++j) {             // j = tap*8 + kb; all idx static
        const int pc = j & 1;
        if (j + 5 < 72) {                      // issue W(j+5): 2 pinned loads
            const int jn = (j + 5) & 7;
            wa[jn][0] = gload16(wb0 + (j + 5) * 1024);
            wa[jn][1] = gload16(wb1 + (j + 5) * 1024);
        }
        if (j + 1 < 72) {
            const int t1 = (j + 1) >> 3, kb1 = (j + 1) & 7;
            const int xo = xoffp[t1] + kb1 * 32;
            xb[pc ^ 1][0] = *(const v4i*)(xs + breg[0] + xo);
            xb[pc ^ 1][1] = *(const v4i*)(xs + breg[1] + xo);
        }
        // counted wait: leave the 10 youngest W loads (iters j+1..j+5) in flight
        if (j <= 66)      asm volatile("s_waitcnt vmcnt(10)" ::: "memory");
        else if (j == 67) asm volatile("s_waitcnt vmcnt(8)"  ::: "memory");
        else if (j == 68) asm volatile("s_waitcnt vmcnt(6)"  ::: "memory");
        else if (j == 69) asm volatile("s_waitcnt vmcnt(4)"  ::: "memory");
        else if (j == 70) asm volatile("s_waitcnt vmcnt(2)"  ::: "memory");
        else              asm volatile("s_waitcnt vmcnt(0)"  ::: "memory");
        __builtin_amdgcn_sched_barrier(0);     // rule #18: MFMA must not hoist past wait

        const int jc = j & 7;
        __builtin_amdgcn_s_setprio(1);
        acc[0][0] = __builtin_amdgcn_mfma_i32_32x32x32_i8(wa[jc][0], xb[pc][0], acc[0][0], 0, 0, 0);
        acc[0][1] = __builtin_amdgcn_mfma_i32_32x32x32_i8(wa[jc][0], xb[pc][1], acc[0][1], 0, 0, 0);
        acc[1][0] = __builtin_amdgcn_mfma_i32_32x32x32_i8(wa[jc][1], xb[pc][0], acc[1][0], 0, 0, 0);
        acc[1][1] = __builtin_amdgcn_mfma_i32_32x32x32_i8(wa[jc][1], xb[pc][1], acc[1][1], 0, 0, 0);
        __builtin_amdgcn_s_setprio(0);
    }

    // C/D: col = lane&31 (spatial), row = (r&3)+8*(r>>2)+4*hi (co)
    #pragma unroll
    for (int mi = 0; mi < 2; ++mi) {
        #pragma unroll
        for (int ni = 0; ni < 2; ++ni) {
            const v16i c = acc[mi][ni];
            int* ob = out + outb[ni] + (wid * 64 + mi * 32 + 4 * hi) * HW2;
            #pragma unroll
            for (int rr = 0; rr < 16; ++rr) {
                __builtin_nontemporal_store(c[rr], ob + ((rr & 3) + 8 * (rr >> 2)) * HW2);
            }
        }
    }
}

// ---------- fallback: direct conv (correct, slow) ----------
__global__ void dc_naive(const int* __restrict__ x, const int* __restrict__ wt,
                         int* __restrict__ out) {
    const int idx = blockIdx.x * 256 + threadIdx.x;
    if (idx >= OUT_TOT) return;
    const int w = idx % HWDIM;
    const int h = (idx / HWDIM) % HWDIM;
    const int co = (idx / HW2) & 255;
    const int n = idx / OUT_NSTR;
    const int* xn = x + n * OUT_NSTR;
    const int* wo = wt + co * (C_IN * 9);
    int acc = 0;
    for (int ci = 0; ci < C_IN; ++ci) {
        const int* xc = xn + ci * HW2;
        const int* wc = wo + ci * 9;
        #pragma unroll
        for (int kh = 0; kh < 3; ++kh) {
            const int hh = h + kh - 1;
            if ((unsigned)hh >= HWDIM) continue;
            #pragma unroll
            for (int kw = 0; kw < 3; ++kw) {
                const int ww = w + kw - 1;
                if ((unsigned)ww >= HWDIM) continue;
                acc += xc[hh * HWDIM + ww] * wc[kh * 3 + kw];
            }
        }
    }
    out[idx] = acc;
}

extern "C" void kernel_launch(void* const* d_in, const int* in_sizes, int n_in,
                              void* d_out, int out_size, void* d_ws, size_t ws_size,
                              hipStream_t stream) {
    const int* x  = (const int*)d_in[0];
    const int* wt = (const int*)d_in[1];
    int* out = (int*)d_out;

    int chunk = 0;
    const int cand[4] = {32, 16, 8, 4};
    for (int i = 0; i < 4; ++i) {
        if ((size_t)cand[i] * XP_IMG + XP_SLACK + WP_BYTES <= ws_size) { chunk = cand[i]; break; }
    }

    if (chunk > 0) {
        char* x8 = (char*)d_ws;
        const size_t x8_bytes = (size_t)chunk * XP_IMG + XP_SLACK;
        unsigned int* wp = (unsigned int*)(x8 + x8_bytes);
        hipLaunchKernelGGL(dc_halo, dim3(chunk), dim3(256), 0, stream, (unsigned int*)x8);
        hipLaunchKernelGGL(dc_pack_w, dim3(576), dim3(256), 0, stream, wt, wp);
        for (int n0 = 0; n0 < N_IMG; n0 += chunk) {
            hipLaunchKernelGGL(dc_x_to_nhwc, dim3(chunk * HWDIM), dim3(256), 0, stream,
                               x, (unsigned int*)x8, n0);
            const int nwg = chunk * TILES_PER_IMG;
            hipLaunchKernelGGL(dc_mfma, dim3(nwg), dim3(256), WIN_B, stream,
                               (const char*)x8, (const char*)wp,
                               out + (size_t)n0 * OUT_NSTR, nwg);
        }
        return;
    }

    hipLaunchKernelGGL(dc_naive, dim3((OUT_TOT + 255) / 256), dim3(256), 0, stream,
                       x, wt, out);
}